// Round 7
// baseline (127.848 us; speedup 1.0000x reference)
//
#include <hip/hip_runtime.h>
#include <math.h>

#define BB 128   // batch
#define TT 8     // seq
#define DD 2048  // model dim
#define RR 4     // TT rank
#define VV 512   // vocab

typedef __attribute__((ext_vector_type(8))) short short8;
typedef __attribute__((ext_vector_type(4))) float v4f;

// barrier WITHOUT the compiler's vmcnt(0) drain: ds ordering only (lgkmcnt(0)),
// global prefetch loads stay in flight across the barrier.
#define BARSYNC() asm volatile("s_waitcnt lgkmcnt(0)\n\ts_barrier" ::: "memory")

__device__ __forceinline__ unsigned pack_bf16(float x, float y) {
    union { float f; unsigned u; } a, b;
    a.f = x; b.f = y;
    unsigned ua = a.u + 0x7fffu + ((a.u >> 16) & 1u);
    unsigned ub = b.u + 0x7fffu + ((b.u >> 16) & 1u);
    return (ua >> 16) | (ub & 0xffff0000u);
}

// ---------------- phase A: T-mean -> fmb(bf16), alpha/beta partial dots ----------------
// grid 256 = (b, half-of-D). Partials written deterministically per (b,half); no atomics.
__global__ __launch_bounds__(256) void phaseA(const float* __restrict__ inp,
                                              const float* __restrict__ w_alpha,
                                              const float* __restrict__ w_beta,
                                              unsigned short* __restrict__ fmb,
                                              float* __restrict__ alphaP,
                                              float* __restrict__ betaP) {
    int bid = blockIdx.x;
    int b = bid >> 1, half = bid & 1;
    int tid = threadIdx.x;

    const float* base = inp + (size_t)b * TT * DD;
    float pa[4] = {0.f, 0.f, 0.f, 0.f};
    float pb[4] = {0.f, 0.f, 0.f, 0.f};
#pragma unroll
    for (int i = 0; i < 4; ++i) {
        int d = half * 1024 + i * 256 + tid;
        float s = 0.f;
#pragma unroll
        for (int t = 0; t < TT; ++t) s += base[t * DD + d];
        float v = s * (1.0f / TT);
        union { float f; unsigned u; } cv; cv.f = v;
        unsigned r = cv.u + 0x7fffu + ((cv.u >> 16) & 1u);
        fmb[b * DD + d] = (unsigned short)(r >> 16);
        float4 wa = *(const float4*)(w_alpha + d * 4);
        float4 wb = *(const float4*)(w_beta + d * 4);
        pa[0] += v * wa.x; pa[1] += v * wa.y; pa[2] += v * wa.z; pa[3] += v * wa.w;
        pb[0] += v * wb.x; pb[1] += v * wb.y; pb[2] += v * wb.z; pb[3] += v * wb.w;
    }
#pragma unroll
    for (int r = 0; r < 4; ++r) {
        for (int m = 1; m < 64; m <<= 1) {
            pa[r] += __shfl_xor(pa[r], m);
            pb[r] += __shfl_xor(pb[r], m);
        }
    }
    __shared__ float sA[4][4], sB[4][4];
    int wid = tid >> 6;
    if ((tid & 63) == 0) {
#pragma unroll
        for (int r = 0; r < 4; ++r) { sA[wid][r] = pa[r]; sB[wid][r] = pb[r]; }
    }
    __syncthreads();
    if (tid < 4) {
        alphaP[b * 8 + half * 4 + tid] = sA[0][tid] + sA[1][tid] + sA[2][tid] + sA[3][tid];
        betaP [b * 8 + half * 4 + tid] = sB[0][tid] + sB[1][tid] + sB[2][tid] + sB[3][tid];
    }
}

// ---------------- phase B: bf16 MFMA GEMM, K-split x4 -> fp32 partial C ----------------
// v7: round-5/6 hot loop verbatim (32-col blocks, chunk=128, named afrA/afrB register
// prefetch, BARSYNC non-draining barriers) but grid 1024 = 256 col-blocks x 4 K-quarters
// -> 4 independent 8-wave blocks per CU (up to 32 waves/CU) interleave their stalls.
// Per-CU wv bytes unchanged (disjoint K). Epilogue = raw fp32 partial-C stores.
__global__ __launch_bounds__(512, 2) void phaseB(const unsigned short* __restrict__ fmb,
                                                 const float* __restrict__ wv,
                                                 float* __restrict__ Cpart) {
    __shared__ unsigned short Ws[2][32][136];  // [buf][n][k+pad], bf16

    const int tid = threadIdx.x;
    const int bid = blockIdx.x;
    const int colb = bid & 255;
    const int qrt  = bid >> 8;        // K-quarter: rows [qrt*512, +512)
    const int col0 = colb * 32;

    const int nq = tid & 7;        // float4 group within 32 cols
    const int kp = tid >> 3;       // 0..63 -> k pair 2kp, 2kp+1 within 128-chunk
    const int w = tid >> 6;        // wave
    const int lane = tid & 63;
    const int m15 = lane & 15;
    const int q = lane >> 4;

    const float* wbase = wv + (size_t)(qrt * 512 + 2 * kp) * 8192 + col0 + nq * 4;
    const unsigned short* abase = fmb + (w * 16 + m15) * DD + qrt * 512 + q * 8;

    v4f acc0 = {0.f, 0.f, 0.f, 0.f};
    v4f acc1 = {0.f, 0.f, 0.f, 0.f};
    short8 afrA[4], afrB[4];       // A-frags for even / odd chunks (register-resident)
    float4 swA0, swA1, swB0, swB1; // wv reg buffers for even / odd chunks

    // prologue: load chunk0 -> swA, chunk1 -> swB; afrA <- chunk0; write chunk0 to Ws[0]
    swA0 = *(const float4*)(wbase);
    swA1 = *(const float4*)(wbase + 8192);
    {
        const float* p = wbase + (size_t)128 * 8192;
        swB0 = *(const float4*)(p);
        swB1 = *(const float4*)(p + 8192);
    }
#pragma unroll
    for (int ks = 0; ks < 4; ++ks) afrA[ks] = *(const short8*)(abase + ks * 32);
    {
        const float* f0 = (const float*)&swA0;
        const float* f1 = (const float*)&swA1;
#pragma unroll
        for (int j = 0; j < 4; ++j)
            *(unsigned*)&Ws[0][nq * 4 + j][2 * kp] = pack_bf16(f0[j], f1[j]);
    }
    BARSYNC();

#pragma unroll
    for (int i = 0; i < 2; ++i) {
        const int c0 = 2 * i;      // even step: MFMA chunk c0 from Ws[0]/afrA
        if (c0 < 2) {              // load chunk c0+2 -> swA
            const float* p = wbase + (size_t)(c0 + 2) * 128 * 8192;
            swA0 = *(const float4*)(p);
            swA1 = *(const float4*)(p + 8192);
        }
        {   // afrB <- chunk c0+1 (L2-resident fmb)
            const unsigned short* ap = abase + (c0 + 1) * 128;
#pragma unroll
            for (int ks = 0; ks < 4; ++ks) afrB[ks] = *(const short8*)(ap + ks * 32);
        }
#pragma unroll
        for (int ks = 0; ks < 4; ++ks) {
            short8 b0 = *(const short8*)&Ws[0][m15][ks * 32 + q * 8];
            short8 b1 = *(const short8*)&Ws[0][16 + m15][ks * 32 + q * 8];
            acc0 = __builtin_amdgcn_mfma_f32_16x16x32_bf16(afrA[ks], b0, acc0, 0, 0, 0);
            acc1 = __builtin_amdgcn_mfma_f32_16x16x32_bf16(afrA[ks], b1, acc1, 0, 0, 0);
        }
        {   // write chunk c0+1 (swB) -> Ws[1]
            const float* f0 = (const float*)&swB0;
            const float* f1 = (const float*)&swB1;
#pragma unroll
            for (int j = 0; j < 4; ++j)
                *(unsigned*)&Ws[1][nq * 4 + j][2 * kp] = pack_bf16(f0[j], f1[j]);
        }
        BARSYNC();

        const int c1 = 2 * i + 1;  // odd step: MFMA chunk c1 from Ws[1]/afrB
        if (c1 < 2) {              // load chunk c1+2 -> swB
            const float* p = wbase + (size_t)(c1 + 2) * 128 * 8192;
            swB0 = *(const float4*)(p);
            swB1 = *(const float4*)(p + 8192);
        }
        if (c1 < 3) {              // afrA <- chunk c1+1
            const unsigned short* ap = abase + (c1 + 1) * 128;
#pragma unroll
            for (int ks = 0; ks < 4; ++ks) afrA[ks] = *(const short8*)(ap + ks * 32);
        }
#pragma unroll
        for (int ks = 0; ks < 4; ++ks) {
            short8 b0 = *(const short8*)&Ws[1][m15][ks * 32 + q * 8];
            short8 b1 = *(const short8*)&Ws[1][16 + m15][ks * 32 + q * 8];
            acc0 = __builtin_amdgcn_mfma_f32_16x16x32_bf16(afrB[ks], b0, acc0, 0, 0, 0);
            acc1 = __builtin_amdgcn_mfma_f32_16x16x32_bf16(afrB[ks], b1, acc1, 0, 0, 0);
        }
        if (c1 < 3) {              // write chunk c1+1 (swA) -> Ws[0]
            const float* f0 = (const float*)&swA0;
            const float* f1 = (const float*)&swA1;
#pragma unroll
            for (int j = 0; j < 4; ++j)
                *(unsigned*)&Ws[0][nq * 4 + j][2 * kp] = pack_bf16(f0[j], f1[j]);
        }
        BARSYNC();
    }

    // epilogue: raw fp32 partial-C stores. D layout: row = q*4+r, col = m15 (+16 for acc1).
    float* cbase = Cpart + (size_t)qrt * (128 * 8192) + col0 + m15;
    const float* a0p = (const float*)&acc0;
    const float* a1p = (const float*)&acc1;
#pragma unroll
    for (int r = 0; r < 4; ++r) {
        int row = w * 16 + q * 4 + r;
        cbase[(size_t)row * 8192]      = a0p[r];
        cbase[(size_t)row * 8192 + 16] = a1p[r];
    }
}

// ---------------- phase CD: combine quarters, abs, marg/sel in LDS, chain, loss ----------
// grid 128 (one block per batch row b), 256 thr. marg/sel never touch global memory.
// u-chain on thread 0, z-chain on thread 64 (different waves -> no divergence serialization).
__global__ __launch_bounds__(256) void phaseCD(const float* __restrict__ Cpart,
                                               const int* __restrict__ labels,
                                               const float* __restrict__ alphaP,
                                               const float* __restrict__ betaP,
                                               float* __restrict__ out) {
    const int b = blockIdx.x;
    const int tid = threadIdx.x;
    __shared__ float smarg[16];
    __shared__ float ssel[TT][16];
    __shared__ float uz[2];

    const float* r0 = Cpart + (size_t)b * 8192;
    const size_t QS = (size_t)128 * 8192;

    // marg: thread t covers cols [t*32, t*32+32); wave w == i-block (cols [w*2048,+2048))
    float pj[4] = {0.f, 0.f, 0.f, 0.f};
    const int base = tid * 32;
#pragma unroll
    for (int g = 0; g < 8; ++g) {
        float4 a0 = *(const float4*)(r0 + base + g * 4);
        float4 a1 = *(const float4*)(r0 + QS + base + g * 4);
        float4 a2 = *(const float4*)(r0 + 2 * QS + base + g * 4);
        float4 a3 = *(const float4*)(r0 + 3 * QS + base + g * 4);
        pj[0] += fabsf(a0.x + a1.x + a2.x + a3.x);
        pj[1] += fabsf(a0.y + a1.y + a2.y + a3.y);
        pj[2] += fabsf(a0.z + a1.z + a2.z + a3.z);
        pj[3] += fabsf(a0.w + a1.w + a2.w + a3.w);
    }
#pragma unroll
    for (int j = 0; j < 4; ++j)
        for (int s = 1; s < 64; s <<= 1) pj[j] += __shfl_xor(pj[j], s);
    const int lane = tid & 63;
    const int wv4 = tid >> 6;
    if (lane == 0) {
#pragma unroll
        for (int j = 0; j < 4; ++j) smarg[wv4 * 4 + j] = pj[j];
    }
    // sel: threads 0..127 -> (t, i, j); C col = i*2048 + label*4 + j
    if (tid < 128) {
        const int t = tid >> 4, ij = tid & 15;
        const int i = ij >> 2, j = ij & 3;
        const int lv = labels[b * 8 + t];
        const size_t col = (size_t)i * 2048 + lv * 4 + j;
        ssel[t][ij] = fabsf(r0[col] + r0[QS + col] + r0[2 * QS + col] + r0[3 * QS + col]);
    }
    __syncthreads();

    if (tid == 0) {
        // u-chain: res = sel[0] * sel[1] * ... * sel[7]
        float res[16], tmp[16];
#pragma unroll
        for (int e = 0; e < 16; ++e) res[e] = ssel[0][e];
        for (int t = 1; t < TT; ++t) {
#pragma unroll
            for (int i = 0; i < 4; ++i)
#pragma unroll
                for (int jj = 0; jj < 4; ++jj) {
                    float s = 0.f;
#pragma unroll
                    for (int k = 0; k < 4; ++k) s += res[i * 4 + k] * ssel[t][k * 4 + jj];
                    tmp[i * 4 + jj] = s;
                }
#pragma unroll
            for (int e = 0; e < 16; ++e) res[e] = tmp[e];
        }
        float u = 0.f;
#pragma unroll
        for (int i = 0; i < 4; ++i) {
            float ai = fabsf(alphaP[b * 8 + i] + alphaP[b * 8 + 4 + i]);
#pragma unroll
            for (int jj = 0; jj < 4; ++jj)
                u += ai * res[i * 4 + jj] * fabsf(betaP[b * 8 + jj] + betaP[b * 8 + 4 + jj]);
        }
        uz[0] = u;
    } else if (tid == 64) {
        // z-chain: zm = marg^(T+1)
        float mm[16], zm[16], tmp[16];
#pragma unroll
        for (int e = 0; e < 16; ++e) { mm[e] = smarg[e]; zm[e] = mm[e]; }
        for (int st = 0; st < TT; ++st) {
#pragma unroll
            for (int i = 0; i < 4; ++i)
#pragma unroll
                for (int jj = 0; jj < 4; ++jj) {
                    float s = 0.f;
#pragma unroll
                    for (int k = 0; k < 4; ++k) s += zm[i * 4 + k] * mm[k * 4 + jj];
                    tmp[i * 4 + jj] = s;
                }
#pragma unroll
            for (int e = 0; e < 16; ++e) zm[e] = tmp[e];
        }
        float z = 0.f;
#pragma unroll
        for (int i = 0; i < 4; ++i) {
            float ai = fabsf(alphaP[b * 8 + i] + alphaP[b * 8 + 4 + i]);
#pragma unroll
            for (int jj = 0; jj < 4; ++jj)
                z += ai * zm[i * 4 + jj] * fabsf(betaP[b * 8 + jj] + betaP[b * 8 + 4 + jj]);
        }
        uz[1] = z;
    }
    __syncthreads();
    if (tid == 0)
        atomicAdd(out, (logf(uz[1]) - logf(uz[0])) * (1.0f / BB));
}

extern "C" void kernel_launch(void* const* d_in, const int* in_sizes, int n_in,
                              void* d_out, int out_size, void* d_ws, size_t ws_size,
                              hipStream_t stream) {
    const float* inp     = (const float*)d_in[0];  // [128,8,2048]
    const int*   labels  = (const int*)d_in[1];    // [128,8]
    const float* w_alpha = (const float*)d_in[2];  // [2048,4]
    const float* w_beta  = (const float*)d_in[3];  // [2048,4]
    const float* wv      = (const float*)d_in[4];  // [2048,8192]
    float* out = (float*)d_out;

    float* ws     = (float*)d_ws;
    float* alphaP = ws;                        // 1024 floats (per b,half,r partials)
    float* betaP  = ws + 1024;                 // 1024 floats
    unsigned short* fmb = (unsigned short*)(ws + 2048);  // 128*2048 bf16 = 131072 floats
    float* Cpart  = ws + 133120;               // 4 x 128 x 8192 fp32 = 16 MB (past fmb)

    phaseA<<<256, 256, 0, stream>>>(inp, w_alpha, w_beta, fmb, alphaP, betaP);
    phaseB<<<1024, 512, 0, stream>>>(fmb, wv, Cpart);
    phaseCD<<<128, 256, 0, stream>>>(Cpart, labels, alphaP, betaP, out);
}